// Round 1
// baseline (1334.523 us; speedup 1.0000x reference)
//
#include <hip/hip_runtime.h>
#include <hip/hip_bf16.h>
#include <math.h>

#define NV 6890
#define BATCH 32
#define C720 720
#define HW 56
#define KBIG 1664
#define NBIG 2048
#define MPAD 6912

// ---------- K1: img_feat [B,720,56,56] -> mx (mean over h), my (mean over w), gT[c][b] (mean both)
__global__ __launch_bounds__(64) void k_img_reduce(const float* __restrict__ img,
    float* __restrict__ mx, float* __restrict__ my, float* __restrict__ gT) {
  int bc = blockIdx.x;                       // b*720+c
  int b = bc / C720, c = bc - b * C720;
  const float* tile = img + (size_t)bc * (HW * HW);
  int lane = threadIdx.x;
  float col = 0.f;
  if (lane < HW) {
    #pragma unroll 8
    for (int h = 0; h < HW; ++h) col += tile[h * HW + lane];
    mx[(size_t)bc * HW + lane] = col * (1.f / HW);
  }
  if (lane < HW) {                           // rows: L1-hot after column pass
    const float* r = tile + lane * HW;
    float row = 0.f;
    #pragma unroll 8
    for (int w = 0; w < HW; ++w) row += r[w];
    my[(size_t)bc * HW + lane] = row * (1.f / HW);
  }
  float t = col;
  #pragma unroll
  for (int off = 32; off > 0; off >>= 1) t += __shfl_down(t, off);
  if (lane == 0) gT[c * BATCH + b] = t * (1.f / (HW * HW));
}

// ---------- K2: Z1T/W1T [r=c*56+l][b] = sum_k W[r,k]*g[b,k] + bias[r]
__global__ __launch_bounds__(256) void k_head1(const float* __restrict__ Wz1, const float* __restrict__ bz1,
    const float* __restrict__ Ww1, const float* __restrict__ bw1,
    const float* __restrict__ gT, float* __restrict__ Z1T, float* __restrict__ W1T) {
  int r = blockIdx.x * 8 + (threadIdx.x >> 5);
  int b = threadIdx.x & 31;
  const float* W = blockIdx.y ? Ww1 : Wz1;
  const float* bias = blockIdx.y ? bw1 : bz1;
  float* out = blockIdx.y ? W1T : Z1T;
  const float* wr = W + (size_t)r * C720;
  float acc = 0.f;
  for (int k = 0; k < C720; k += 4) {
    float4 wv = *(const float4*)(wr + k);
    acc += wv.x * gT[(k    ) * 32 + b];
    acc += wv.y * gT[(k + 1) * 32 + b];
    acc += wv.z * gT[(k + 2) * 32 + b];
    acc += wv.w * gT[(k + 3) * 32 + b];
  }
  out[r * 32 + b] = acc + bias[r];
}

// ---------- K3: w1m[c][b] = mean_l W1T[(c*56+l)][b]
__global__ __launch_bounds__(256) void k_w1m(const float* __restrict__ W1T, float* __restrict__ w1m) {
  int t = blockIdx.x * 256 + threadIdx.x;
  if (t >= 224 * 32) return;
  int c = t >> 5, b = t & 31;
  float s = 0.f;
  for (int l = 0; l < HW; ++l) s += W1T[(c * HW + l) * 32 + b];
  w1m[t] = s * (1.f / HW);
}

// ---------- K4: coord_w -> out[...,3]
__global__ __launch_bounds__(256) void k_coordw(const float* __restrict__ Ww2, const float* __restrict__ bw2,
    const float* __restrict__ w1m, float* __restrict__ out) {
  int v = blockIdx.x * 8 + (threadIdx.x >> 5);
  int b = threadIdx.x & 31;
  if (v >= NV) return;
  const float* wr = Ww2 + (size_t)v * 224;
  float acc = 0.f;
  for (int c = 0; c < 224; c += 4) {
    float4 wv = *(const float4*)(wr + c);
    acc += wv.x * w1m[(c    ) * 32 + b];
    acc += wv.y * w1m[(c + 1) * 32 + b];
    acc += wv.z * w1m[(c + 2) * 32 + b];
    acc += wv.w * w1m[(c + 3) * 32 + b];
  }
  acc += bw2[v];
  out[((size_t)b * NV + v) * 4 + 3] = 1.f / (1.f + expf(-acc));
}

// ---------- K5: S[3][64] column sums of Wg1 blocks
__global__ void k_S(const float* __restrict__ Wg1, float* __restrict__ S) {
  int j = threadIdx.x;
  float s0 = 0, s1 = 0, s2 = 0;
  for (int l = 0; l < HW; ++l) {
    s0 += Wg1[l * 64 + j];
    s1 += Wg1[(HW + l) * 64 + j];
    s2 += Wg1[(112 + l) * 64 + j];
  }
  S[j] = s0; S[64 + j] = s1; S[128 + j] = s2;
}

// ---------- K6: P[c'][b*64+j] = Ax / Ay / Az
__global__ __launch_bounds__(64) void k_passem(const float* __restrict__ mx, const float* __restrict__ my,
    const float* __restrict__ Z1T, const float* __restrict__ Wg1, float* __restrict__ P) {
  int cp = blockIdx.x, b = blockIdx.y, j = threadIdx.x;
  float acc = 0.f;
  if (cp < 720) {
    const float* x = mx + ((size_t)b * C720 + cp) * HW;
    for (int l = 0; l < HW; ++l) acc += x[l] * Wg1[l * 64 + j];
  } else if (cp < 1440) {
    const float* x = my + ((size_t)b * C720 + (cp - 720)) * HW;
    for (int l = 0; l < HW; ++l) acc += x[l] * Wg1[(HW + l) * 64 + j];
  } else {
    int c = cp - 1440;
    for (int l = 0; l < HW; ++l) acc += Z1T[(c * HW + l) * 32 + b] * Wg1[(112 + l) * 64 + j];
  }
  P[(size_t)cp * NBIG + b * 64 + j] = acc;
}

// ---------- K7: Wcat [6912][1664] = [Wx | Wy | Wz2], zero-padded rows
__global__ __launch_bounds__(256) void k_wcat(const float* __restrict__ Wx, const float* __restrict__ Wy,
    const float* __restrict__ Wz2, float* __restrict__ Wcat) {
  int c = blockIdx.x * 256 + threadIdx.x;
  int v = blockIdx.y;
  if (c >= KBIG) return;
  float val = 0.f;
  if (v < NV) {
    if (c < 720)       val = Wx[(size_t)v * 720 + c];
    else if (c < 1440) val = Wy[(size_t)v * 720 + (c - 720)];
    else               val = Wz2[(size_t)v * 224 + (c - 1440)];
  }
  Wcat[(size_t)v * KBIG + c] = val;
}

// ---------- K8: fp32 SGEMM 128x128x16, 8x8 microtile. U[b][v][64] += rank-1 biases
__global__ __launch_bounds__(256) void k_biggemm(const float* __restrict__ A, const float* __restrict__ Bm,
    const float* __restrict__ bx, const float* __restrict__ by, const float* __restrict__ bz2,
    const float* __restrict__ S, float* __restrict__ U) {
  __shared__ float As[16][132];
  __shared__ float Bs[16][128];
  const int m0 = blockIdx.x * 128, n0 = blockIdx.y * 128;
  const int tid = threadIdx.x;
  const int arow = tid >> 1, ak = (tid & 1) * 8;
  const int brow = tid >> 4, bcol = (tid & 15) * 8;
  const int ty = tid >> 4, tx = tid & 15;
  const float* Aptr = A + (size_t)(m0 + arow) * KBIG + ak;
  const float* Bptr = Bm + (size_t)brow * NBIG + n0 + bcol;
  float acc[8][8] = {};
  for (int kt = 0; kt < KBIG; kt += 16) {
    float4 a0 = *(const float4*)(Aptr + kt);
    float4 a1 = *(const float4*)(Aptr + kt + 4);
    float4 b0 = *(const float4*)(Bptr + (size_t)kt * NBIG);
    float4 b1 = *(const float4*)(Bptr + (size_t)kt * NBIG + 4);
    As[ak + 0][arow] = a0.x; As[ak + 1][arow] = a0.y; As[ak + 2][arow] = a0.z; As[ak + 3][arow] = a0.w;
    As[ak + 4][arow] = a1.x; As[ak + 5][arow] = a1.y; As[ak + 6][arow] = a1.z; As[ak + 7][arow] = a1.w;
    *(float4*)&Bs[brow][bcol] = b0;
    *(float4*)&Bs[brow][bcol + 4] = b1;
    __syncthreads();
    #pragma unroll
    for (int k = 0; k < 16; ++k) {
      float av[8], bv[8];
      *(float4*)&av[0] = *(const float4*)&As[k][ty * 8];
      *(float4*)&av[4] = *(const float4*)&As[k][ty * 8 + 4];
      *(float4*)&bv[0] = *(const float4*)&Bs[k][tx * 8];
      *(float4*)&bv[4] = *(const float4*)&Bs[k][tx * 8 + 4];
      #pragma unroll
      for (int i = 0; i < 8; ++i)
        #pragma unroll
        for (int j = 0; j < 8; ++j) acc[i][j] += av[i] * bv[j];
    }
    __syncthreads();
  }
  #pragma unroll
  for (int i = 0; i < 8; ++i) {
    int v = m0 + ty * 8 + i;
    if (v >= NV) continue;
    float bxv = bx[v], byv = by[v], bzv = bz2[v];
    #pragma unroll
    for (int j = 0; j < 8; ++j) {
      int n = n0 + tx * 8 + j;
      int bb = n >> 6, jj = n & 63;
      U[((size_t)bb * NV + v) * 64 + jj] = acc[i][j] + bxv * S[jj] + byv * S[64 + jj] + bzv * S[128 + jj];
    }
  }
}

// ---------- graph prep
__global__ __launch_bounds__(256) void k_deg_init(float* deg) {
  int v = blockIdx.x * 256 + threadIdx.x;
  if (v < NV) deg[v] = 1.f;                 // self-loop
}
__global__ __launch_bounds__(256) void k_deg_count(const int* __restrict__ ei, float* deg, int E) {
  int e = blockIdx.x * 256 + threadIdx.x;
  if (e < E) atomicAdd(&deg[ei[E + e]], 1.f);
}
__global__ __launch_bounds__(256) void k_dinv(const float* __restrict__ deg, float* __restrict__ dinv) {
  int v = blockIdx.x * 256 + threadIdx.x;
  if (v < NV) dinv[v] = rsqrtf(deg[v]);
}
__global__ __launch_bounds__(1024) void k_scan(const float* __restrict__ deg, int* rowptr, int* cursor) {
  __shared__ int sdata[1024];
  const int PER = 7;                        // 1024*7 >= 6890
  int tid = threadIdx.x;
  int base = tid * PER;
  int loc[PER]; int tot = 0;
  for (int i = 0; i < PER; ++i) {
    int idx = base + i;
    int cnt = (idx < NV) ? (int)deg[idx] : 0;
    loc[i] = tot; tot += cnt;
  }
  sdata[tid] = tot; __syncthreads();
  for (int off = 1; off < 1024; off <<= 1) {
    int vcur = sdata[tid];
    int add = (tid >= off) ? sdata[tid - off] : 0;
    __syncthreads();
    sdata[tid] = vcur + add;
    __syncthreads();
  }
  int excl = sdata[tid] - tot;
  for (int i = 0; i < PER; ++i) {
    int idx = base + i;
    if (idx < NV) { rowptr[idx] = excl + loc[i]; cursor[idx] = 0; }
  }
  if (tid == 1023) rowptr[NV] = sdata[1023];
}
__global__ __launch_bounds__(256) void k_fill(const int* __restrict__ ei, const int* __restrict__ rowptr,
    int* cursor, int* col, int E) {
  int i = blockIdx.x * 256 + threadIdx.x;
  int N = E + NV;
  if (i >= N) return;
  int s, d;
  if (i < E) { s = ei[i]; d = ei[E + i]; } else { s = d = i - E; }
  int pos = atomicAdd(&cursor[d], 1);
  col[rowptr[d] + pos] = s;
}

// ---------- GCN layers
__global__ __launch_bounds__(256) void k_agg1(const float* __restrict__ U, const int* __restrict__ rowptr,
    const int* __restrict__ col, const float* __restrict__ dinv, const float* __restrict__ bg1,
    float* __restrict__ h1) {
  int w = blockIdx.x * 4 + (threadIdx.x >> 6);
  int lane = threadIdx.x & 63;
  int b = w / NV, v = w - b * NV;
  int r0 = rowptr[v], r1 = rowptr[v + 1];
  const float* base = U + (size_t)b * NV * 64;
  float acc = 0.f;
  for (int i = r0; i < r1; ++i) {
    int u = col[i];
    acc += dinv[u] * base[(size_t)u * 64 + lane];
  }
  acc = acc * dinv[v] + bg1[lane];
  h1[((size_t)b * NV + v) * 64 + lane] = acc > 0.f ? acc : 0.01f * acc;
}
__global__ __launch_bounds__(256) void k_gemm2(const float* __restrict__ h1, const float* __restrict__ Wg2,
    float* __restrict__ xw2) {
  __shared__ float w[64 * 32];
  for (int i = threadIdx.x; i < 2048; i += 256) w[i] = Wg2[i];
  __syncthreads();
  int row = blockIdx.x * 8 + (threadIdx.x >> 5);
  int j2 = threadIdx.x & 31;
  const float* hr = h1 + (size_t)row * 64;
  float acc = 0.f;
  #pragma unroll
  for (int j = 0; j < 64; j += 4) {
    float4 hv = *(const float4*)(hr + j);
    acc += hv.x * w[(j    ) * 32 + j2];
    acc += hv.y * w[(j + 1) * 32 + j2];
    acc += hv.z * w[(j + 2) * 32 + j2];
    acc += hv.w * w[(j + 3) * 32 + j2];
  }
  xw2[(size_t)row * 32 + j2] = acc;
}
__global__ __launch_bounds__(256) void k_agg2(const float* __restrict__ xw2, const int* __restrict__ rowptr,
    const int* __restrict__ col, const float* __restrict__ dinv, const float* __restrict__ bg2,
    float* __restrict__ h2) {
  int w = blockIdx.x * 4 + (threadIdx.x >> 6);   // wave over 32*(NV/2)
  int lane = threadIdx.x & 63;
  int b = w / (NV / 2), p = w - b * (NV / 2);
  int v = p * 2 + (lane >> 5);
  int j2 = lane & 31;
  int r0 = rowptr[v], r1 = rowptr[v + 1];
  const float* base = xw2 + (size_t)b * NV * 32;
  float acc = 0.f;
  for (int i = r0; i < r1; ++i) {
    int u = col[i];
    acc += dinv[u] * base[(size_t)u * 32 + j2];
  }
  acc = acc * dinv[v] + bg2[j2];
  h2[((size_t)b * NV + v) * 32 + j2] = acc > 0.f ? acc : 0.01f * acc;
}
__global__ __launch_bounds__(256) void k_gemm3(const float* __restrict__ h2, const float* __restrict__ Wg3,
    float* __restrict__ xw3) {
  __shared__ float w[96];
  if (threadIdx.x < 96) w[threadIdx.x] = Wg3[threadIdx.x];
  __syncthreads();
  int row = blockIdx.x * 256 + threadIdx.x;
  if (row >= BATCH * NV) return;
  const float* hr = h2 + (size_t)row * 32;
  float a0 = 0, a1 = 0, a2 = 0;
  #pragma unroll
  for (int j = 0; j < 32; ++j) {
    float hv = hr[j];
    a0 += hv * w[j * 3 + 0];
    a1 += hv * w[j * 3 + 1];
    a2 += hv * w[j * 3 + 2];
  }
  float4 o; o.x = a0; o.y = a1; o.z = a2; o.w = 0.f;
  *(float4*)(xw3 + (size_t)row * 4) = o;
}
__global__ __launch_bounds__(256) void k_agg3(const float* __restrict__ xw3, const int* __restrict__ rowptr,
    const int* __restrict__ col, const float* __restrict__ dinv, const float* __restrict__ bg3,
    float* __restrict__ out) {
  int t = blockIdx.x * 256 + threadIdx.x;
  if (t >= BATCH * NV) return;
  int b = t / NV, v = t - b * NV;
  int r0 = rowptr[v], r1 = rowptr[v + 1];
  const float* base = xw3 + (size_t)b * NV * 4;
  float a0 = 0, a1 = 0, a2 = 0;
  for (int i = r0; i < r1; ++i) {
    int u = col[i];
    float wt = dinv[u];
    float4 x = *(const float4*)(base + (size_t)u * 4);
    a0 += wt * x.x; a1 += wt * x.y; a2 += wt * x.z;
  }
  float dv = dinv[v];
  float* o = out + (size_t)t * 4;
  o[0] = a0 * dv + bg3[0];
  o[1] = a1 * dv + bg3[1];
  o[2] = a2 * dv + bg3[2];
}

extern "C" void kernel_launch(void* const* d_in, const int* in_sizes, int n_in,
                              void* d_out, int out_size, void* d_ws, size_t ws_size,
                              hipStream_t stream) {
  const float* img = (const float*)d_in[0];
  const int*   ei  = (const int*)d_in[1];
  const float* Wx  = (const float*)d_in[2];
  const float* bx  = (const float*)d_in[3];
  const float* Wy  = (const float*)d_in[4];
  const float* by  = (const float*)d_in[5];
  const float* Wz1 = (const float*)d_in[6];
  const float* bz1 = (const float*)d_in[7];
  const float* Wz2 = (const float*)d_in[8];
  const float* bz2 = (const float*)d_in[9];
  const float* Ww1 = (const float*)d_in[10];
  const float* bw1 = (const float*)d_in[11];
  const float* Ww2 = (const float*)d_in[12];
  const float* bw2 = (const float*)d_in[13];
  const float* Wg1 = (const float*)d_in[14];
  const float* bg1 = (const float*)d_in[15];
  const float* Wg2 = (const float*)d_in[16];
  const float* bg2 = (const float*)d_in[17];
  const float* Wg3 = (const float*)d_in[18];
  const float* bg3 = (const float*)d_in[19];
  float* out = (float*)d_out;
  int E = in_sizes[1] / 2;

  char* ws = (char*)d_ws;
  float* U    = (float*)(ws + 0ULL);           // 56,442,880 B  [b][v][64]
  float* h1   = (float*)(ws + 56442880ULL);    // 56,442,880 B
  float* Wcat = (float*)(ws + 112885760ULL);   // 46,006,272 B  [6912][1664]
  float* P    = (float*)(ws + 158892032ULL);   // 13,631,488 B  [1664][2048]
  float* mx   = (float*)(ws + 172523520ULL);   //  5,160,960 B
  float* my   = (float*)(ws + 177684480ULL);   //  5,160,960 B
  float* Z1T  = (float*)(ws + 182845440ULL);   //  1,605,632 B
  float* W1T  = (float*)(ws + 184451072ULL);   //  1,605,632 B
  float* gT   = (float*)(ws + 186056704ULL);   //     92,160 B  [720][32]
  float* w1m  = (float*)(ws + 186148864ULL);   //     28,672 B  [224][32]
  float* S    = (float*)(ws + 186177536ULL);   //      1,024 B
  float* deg  = (float*)(ws + 186178560ULL);
  float* dinv = (float*)(ws + 186206208ULL);
  int* rowptr = (int*)(ws + 186233856ULL);
  int* cursor = (int*)(ws + 186261504ULL);
  int* colx   = (int*)(ws + 186289152ULL);     // 192,872 B (E+V entries)
  float* xw2 = Wcat;   // alias: Wcat dead after k_biggemm
  float* h2  = U;      // alias: U dead after k_agg1
  float* xw3 = P;      // alias: P dead after k_biggemm

  // graph prep (input-only dependence)
  k_deg_init<<<(NV + 255) / 256, 256, 0, stream>>>(deg);
  k_deg_count<<<(E + 255) / 256, 256, 0, stream>>>(ei, deg, E);
  k_dinv<<<(NV + 255) / 256, 256, 0, stream>>>(deg, dinv);
  k_scan<<<1, 1024, 0, stream>>>(deg, rowptr, cursor);
  k_fill<<<(E + NV + 255) / 256, 256, 0, stream>>>(ei, rowptr, cursor, colx, E);

  // heads
  k_img_reduce<<<BATCH * C720, 64, 0, stream>>>(img, mx, my, gT);
  k_head1<<<dim3(12544 / 8, 2), 256, 0, stream>>>(Wz1, bz1, Ww1, bw1, gT, Z1T, W1T);
  k_w1m<<<(224 * 32 + 255) / 256, 256, 0, stream>>>(W1T, w1m);
  k_coordw<<<(NV + 7) / 8, 256, 0, stream>>>(Ww2, bw2, w1m, out);
  k_S<<<1, 64, 0, stream>>>(Wg1, S);
  k_passem<<<dim3(KBIG, BATCH), 64, 0, stream>>>(mx, my, Z1T, Wg1, P);
  k_wcat<<<dim3(7, MPAD), 256, 0, stream>>>(Wx, Wy, Wz2, Wcat);
  k_biggemm<<<dim3(MPAD / 128, NBIG / 128), 256, 0, stream>>>(Wcat, P, bx, by, bz2, S, U);

  // GCN
  k_agg1<<<BATCH * NV / 4, 256, 0, stream>>>(U, rowptr, colx, dinv, bg1, h1);
  k_gemm2<<<BATCH * NV / 8, 256, 0, stream>>>(h1, Wg2, xw2);
  k_agg2<<<BATCH * (NV / 2) / 4, 256, 0, stream>>>(xw2, rowptr, colx, dinv, bg2, h2);
  k_gemm3<<<(BATCH * NV + 255) / 256, 256, 0, stream>>>(h2, Wg3, xw3);
  k_agg3<<<(BATCH * NV + 255) / 256, 256, 0, stream>>>(xw3, rowptr, colx, dinv, bg3, out);
}

// Round 2
// 798.793 us; speedup vs baseline: 1.6707x; 1.6707x over previous
//
#include <hip/hip_runtime.h>
#include <hip/hip_bf16.h>
#include <math.h>

#define NV 6890
#define BATCH 32
#define C720 720
#define HW 56
#define KBIG 1664
#define NBIG 2048
#define MPAD 6912

typedef __attribute__((ext_vector_type(8))) short bf16x8;
typedef __attribute__((ext_vector_type(4))) float f32x4;

__device__ inline void gload16(const void* g, void* l) {
  __builtin_amdgcn_global_load_lds((const __attribute__((address_space(1))) void*)g,
                                   (__attribute__((address_space(3))) void*)l, 16, 0, 0);
}

// ---------- K1: img_feat [B,720,56,56] -> mx (mean over h), my (mean over w), gT[c][b]
__global__ __launch_bounds__(64) void k_img_reduce(const float* __restrict__ img,
    float* __restrict__ mx, float* __restrict__ my, float* __restrict__ gT) {
  int bc = blockIdx.x;                       // b*720+c
  int b = bc / C720, c = bc - b * C720;
  const float* tile = img + (size_t)bc * (HW * HW);
  int lane = threadIdx.x;
  float col = 0.f;
  if (lane < HW) {
    #pragma unroll 8
    for (int h = 0; h < HW; ++h) col += tile[h * HW + lane];
    mx[(size_t)bc * HW + lane] = col * (1.f / HW);
  }
  if (lane < HW) {
    const float* r = tile + lane * HW;
    float row = 0.f;
    #pragma unroll 8
    for (int w = 0; w < HW; ++w) row += r[w];
    my[(size_t)bc * HW + lane] = row * (1.f / HW);
  }
  float t = col;
  #pragma unroll
  for (int off = 32; off > 0; off >>= 1) t += __shfl_down(t, off);
  if (lane == 0) gT[c * BATCH + b] = t * (1.f / (HW * HW));
}

// ---------- K2: Z1T/W1T [r][b] = sum_k W[r,k]*g[b,k] + bias[r]
__global__ __launch_bounds__(256) void k_head1(const float* __restrict__ Wz1, const float* __restrict__ bz1,
    const float* __restrict__ Ww1, const float* __restrict__ bw1,
    const float* __restrict__ gT, float* __restrict__ Z1T, float* __restrict__ W1T) {
  int r = blockIdx.x * 8 + (threadIdx.x >> 5);
  int b = threadIdx.x & 31;
  const float* W = blockIdx.y ? Ww1 : Wz1;
  const float* bias = blockIdx.y ? bw1 : bz1;
  float* out = blockIdx.y ? W1T : Z1T;
  const float* wr = W + (size_t)r * C720;
  float acc = 0.f;
  for (int k = 0; k < C720; k += 4) {
    float4 wv = *(const float4*)(wr + k);
    acc += wv.x * gT[(k    ) * 32 + b];
    acc += wv.y * gT[(k + 1) * 32 + b];
    acc += wv.z * gT[(k + 2) * 32 + b];
    acc += wv.w * gT[(k + 3) * 32 + b];
  }
  out[r * 32 + b] = acc + bias[r];
}

// ---------- K3: w1m[c][b] = mean_l W1T[(c*56+l)][b]
__global__ __launch_bounds__(256) void k_w1m(const float* __restrict__ W1T, float* __restrict__ w1m) {
  int t = blockIdx.x * 256 + threadIdx.x;
  if (t >= 224 * 32) return;
  int c = t >> 5, b = t & 31;
  float s = 0.f;
  for (int l = 0; l < HW; ++l) s += W1T[(c * HW + l) * 32 + b];
  w1m[t] = s * (1.f / HW);
}

// ---------- K4: coord_w -> out[...,3]
__global__ __launch_bounds__(256) void k_coordw(const float* __restrict__ Ww2, const float* __restrict__ bw2,
    const float* __restrict__ w1m, float* __restrict__ out) {
  int v = blockIdx.x * 8 + (threadIdx.x >> 5);
  int b = threadIdx.x & 31;
  if (v >= NV) return;
  const float* wr = Ww2 + (size_t)v * 224;
  float acc = 0.f;
  for (int c = 0; c < 224; c += 4) {
    float4 wv = *(const float4*)(wr + c);
    acc += wv.x * w1m[(c    ) * 32 + b];
    acc += wv.y * w1m[(c + 1) * 32 + b];
    acc += wv.z * w1m[(c + 2) * 32 + b];
    acc += wv.w * w1m[(c + 3) * 32 + b];
  }
  acc += bw2[v];
  out[((size_t)b * NV + v) * 4 + 3] = 1.f / (1.f + expf(-acc));
}

// ---------- K5: S[3][64] column sums of Wg1 blocks
__global__ void k_S(const float* __restrict__ Wg1, float* __restrict__ S) {
  int j = threadIdx.x;
  float s0 = 0, s1 = 0, s2 = 0;
  for (int l = 0; l < HW; ++l) {
    s0 += Wg1[l * 64 + j];
    s1 += Wg1[(HW + l) * 64 + j];
    s2 += Wg1[(112 + l) * 64 + j];
  }
  S[j] = s0; S[64 + j] = s1; S[128 + j] = s2;
}

// ---------- K6: P[cp][b*64+j]  (fp32, N-major)
__global__ __launch_bounds__(64) void k_passem(const float* __restrict__ mx, const float* __restrict__ my,
    const float* __restrict__ Z1T, const float* __restrict__ Wg1, float* __restrict__ P) {
  int cp = blockIdx.x, b = blockIdx.y, j = threadIdx.x;
  float acc = 0.f;
  if (cp < 720) {
    const float* x = mx + ((size_t)b * C720 + cp) * HW;
    for (int l = 0; l < HW; ++l) acc += x[l] * Wg1[l * 64 + j];
  } else if (cp < 1440) {
    const float* x = my + ((size_t)b * C720 + (cp - 720)) * HW;
    for (int l = 0; l < HW; ++l) acc += x[l] * Wg1[(HW + l) * 64 + j];
  } else {
    int c = cp - 1440;
    for (int l = 0; l < HW; ++l) acc += Z1T[(c * HW + l) * 32 + b] * Wg1[(112 + l) * 64 + j];
  }
  P[(size_t)cp * NBIG + b * 64 + j] = acc;
}

// ---------- K6b: transpose-convert P[k][n] fp32 -> PT[n][k] bf16
__global__ __launch_bounds__(256) void k_transp(const float* __restrict__ P, __hip_bfloat16* __restrict__ PT) {
  __shared__ __hip_bfloat16 t[64][66];
  int k0 = blockIdx.x * 64, n0 = blockIdx.y * 64;
  int tx = threadIdx.x & 63, ty4 = threadIdx.x >> 6;
  #pragma unroll
  for (int i = 0; i < 16; ++i) {
    int k = ty4 * 16 + i;
    t[k][tx] = (__hip_bfloat16)P[(size_t)(k0 + k) * NBIG + n0 + tx];
  }
  __syncthreads();
  #pragma unroll
  for (int i = 0; i < 16; ++i) {
    int n = ty4 * 16 + i;
    PT[(size_t)(n0 + n) * KBIG + k0 + tx] = t[tx][n];
  }
}

// ---------- K7: Wcatb [6912][1664] bf16 = [Wx | Wy | Wz2], zero-padded rows
__global__ __launch_bounds__(256) void k_wcat(const float* __restrict__ Wx, const float* __restrict__ Wy,
    const float* __restrict__ Wz2, __hip_bfloat16* __restrict__ Wcatb) {
  int c = blockIdx.x * 256 + threadIdx.x;
  int v = blockIdx.y;
  if (c >= KBIG) return;
  float val = 0.f;
  if (v < NV) {
    if (c < 720)       val = Wx[(size_t)v * 720 + c];
    else if (c < 1440) val = Wy[(size_t)v * 720 + (c - 720)];
    else               val = Wz2[(size_t)v * 224 + (c - 1440)];
  }
  Wcatb[(size_t)v * KBIG + c] = (__hip_bfloat16)val;
}

// ---------- K8: bf16 MFMA GEMM  C[MPAD][NBIG] = A[MPAD][K] * BT[NBIG][K]^T  (m97 structure)
// 128x128 tile, BK=64, 4 waves each computing a 64x64 sub-tile (4x4 frags of 16x16x32).
__global__ __launch_bounds__(256) void k_mfma_gemm(
    const __hip_bfloat16* __restrict__ A, const __hip_bfloat16* __restrict__ BT,
    const float* __restrict__ bx, const float* __restrict__ by, const float* __restrict__ bz2,
    const float* __restrict__ S, float* __restrict__ U) {
  __shared__ __hip_bfloat16 As[128 * 64];
  __shared__ __hip_bfloat16 Bs[128 * 64];
  const int tid = threadIdx.x;
  const int wid = tid >> 6, lane = tid & 63;
  const int m0 = blockIdx.x * 128, n0 = blockIdx.y * 128;
  const int wr = wid >> 1, wc = wid & 1;
  const int l15 = lane & 15, lhi = lane >> 4;
  const int lk = lhi * 8;

  f32x4 acc[4][4];
  #pragma unroll
  for (int i = 0; i < 4; ++i)
    #pragma unroll
    for (int j = 0; j < 4; ++j) acc[i][j] = (f32x4){0.f, 0.f, 0.f, 0.f};

  // staging: thread loads 8 bf16 (16B); 4 passes cover a 128x64 tile
  const __hip_bfloat16* ag = A  + (size_t)(m0 + (tid >> 3)) * KBIG + (tid & 7) * 8;
  const __hip_bfloat16* bg = BT + (size_t)(n0 + (tid >> 3)) * KBIG + (tid & 7) * 8;
  const int lbase = wid * 512;               // element offset; HW adds lane*8

  for (int kt = 0; kt < KBIG; kt += 64) {
    #pragma unroll
    for (int p = 0; p < 4; ++p) {
      gload16(ag + kt + (size_t)(p * 32) * KBIG, (void*)&As[p * 2048 + lbase]);
      gload16(bg + kt + (size_t)(p * 32) * KBIG, (void*)&Bs[p * 2048 + lbase]);
    }
    __syncthreads();
    #pragma unroll
    for (int ks = 0; ks < 2; ++ks) {
      bf16x8 af[4], bf[4];
      #pragma unroll
      for (int mf = 0; mf < 4; ++mf)
        af[mf] = *(const bf16x8*)&As[(wr * 64 + mf * 16 + l15) * 64 + ks * 32 + lk];
      #pragma unroll
      for (int nf = 0; nf < 4; ++nf)
        bf[nf] = *(const bf16x8*)&Bs[(wc * 64 + nf * 16 + l15) * 64 + ks * 32 + lk];
      #pragma unroll
      for (int mf = 0; mf < 4; ++mf)
        #pragma unroll
        for (int nf = 0; nf < 4; ++nf)
          acc[mf][nf] = __builtin_amdgcn_mfma_f32_16x16x32_bf16(af[mf], bf[nf], acc[mf][nf], 0, 0, 0);
    }
    __syncthreads();
  }

  // epilogue: U[b][v][64] = acc + rank-1 biases
  float s0[4], s1[4], s2[4];
  #pragma unroll
  for (int nf = 0; nf < 4; ++nf) {
    int jj = nf * 16 + l15;
    s0[nf] = S[jj]; s1[nf] = S[64 + jj]; s2[nf] = S[128 + jj];
  }
  float* Ub = U + (size_t)((n0 >> 6) + wc) * NV * 64;
  #pragma unroll
  for (int mf = 0; mf < 4; ++mf) {
    #pragma unroll
    for (int r = 0; r < 4; ++r) {
      int v = m0 + wr * 64 + mf * 16 + lhi * 4 + r;
      if (v >= NV) continue;
      float bxv = bx[v], byv = by[v], bzv = bz2[v];
      #pragma unroll
      for (int nf = 0; nf < 4; ++nf) {
        int jj = nf * 16 + l15;
        Ub[(size_t)v * 64 + jj] = acc[mf][nf][r] + bxv * s0[nf] + byv * s1[nf] + bzv * s2[nf];
      }
    }
  }
}

// ---------- graph prep
__global__ __launch_bounds__(256) void k_deg_init(float* deg) {
  int v = blockIdx.x * 256 + threadIdx.x;
  if (v < NV) deg[v] = 1.f;
}
__global__ __launch_bounds__(256) void k_deg_count(const int* __restrict__ ei, float* deg, int E) {
  int e = blockIdx.x * 256 + threadIdx.x;
  if (e < E) atomicAdd(&deg[ei[E + e]], 1.f);
}
__global__ __launch_bounds__(256) void k_dinv(const float* __restrict__ deg, float* __restrict__ dinv) {
  int v = blockIdx.x * 256 + threadIdx.x;
  if (v < NV) dinv[v] = rsqrtf(deg[v]);
}
__global__ __launch_bounds__(1024) void k_scan(const float* __restrict__ deg, int* rowptr, int* cursor) {
  __shared__ int sdata[1024];
  const int PER = 7;
  int tid = threadIdx.x;
  int base = tid * PER;
  int loc[PER]; int tot = 0;
  for (int i = 0; i < PER; ++i) {
    int idx = base + i;
    int cnt = (idx < NV) ? (int)deg[idx] : 0;
    loc[i] = tot; tot += cnt;
  }
  sdata[tid] = tot; __syncthreads();
  for (int off = 1; off < 1024; off <<= 1) {
    int vcur = sdata[tid];
    int add = (tid >= off) ? sdata[tid - off] : 0;
    __syncthreads();
    sdata[tid] = vcur + add;
    __syncthreads();
  }
  int excl = sdata[tid] - tot;
  for (int i = 0; i < PER; ++i) {
    int idx = base + i;
    if (idx < NV) { rowptr[idx] = excl + loc[i]; cursor[idx] = 0; }
  }
  if (tid == 1023) rowptr[NV] = sdata[1023];
}
__global__ __launch_bounds__(256) void k_fill(const int* __restrict__ ei, const int* __restrict__ rowptr,
    int* cursor, int* col, int E) {
  int i = blockIdx.x * 256 + threadIdx.x;
  int N = E + NV;
  if (i >= N) return;
  int s, d;
  if (i < E) { s = ei[i]; d = ei[E + i]; } else { s = d = i - E; }
  int pos = atomicAdd(&cursor[d], 1);
  col[rowptr[d] + pos] = s;
}

// ---------- GCN layers
__global__ __launch_bounds__(256) void k_agg1(const float* __restrict__ U, const int* __restrict__ rowptr,
    const int* __restrict__ col, const float* __restrict__ dinv, const float* __restrict__ bg1,
    float* __restrict__ h1) {
  int w = blockIdx.x * 4 + (threadIdx.x >> 6);
  int lane = threadIdx.x & 63;
  int b = w / NV, v = w - b * NV;
  int r0 = rowptr[v], r1 = rowptr[v + 1];
  const float* base = U + (size_t)b * NV * 64;
  float acc = 0.f;
  for (int i = r0; i < r1; ++i) {
    int u = col[i];
    acc += dinv[u] * base[(size_t)u * 64 + lane];
  }
  acc = acc * dinv[v] + bg1[lane];
  h1[((size_t)b * NV + v) * 64 + lane] = acc > 0.f ? acc : 0.01f * acc;
}
__global__ __launch_bounds__(256) void k_gemm2(const float* __restrict__ h1, const float* __restrict__ Wg2,
    float* __restrict__ xw2) {
  __shared__ float w[64 * 32];
  for (int i = threadIdx.x; i < 2048; i += 256) w[i] = Wg2[i];
  __syncthreads();
  int row = blockIdx.x * 8 + (threadIdx.x >> 5);
  int j2 = threadIdx.x & 31;
  const float* hr = h1 + (size_t)row * 64;
  float acc = 0.f;
  #pragma unroll
  for (int j = 0; j < 64; j += 4) {
    float4 hv = *(const float4*)(hr + j);
    acc += hv.x * w[(j    ) * 32 + j2];
    acc += hv.y * w[(j + 1) * 32 + j2];
    acc += hv.z * w[(j + 2) * 32 + j2];
    acc += hv.w * w[(j + 3) * 32 + j2];
  }
  xw2[(size_t)row * 32 + j2] = acc;
}
__global__ __launch_bounds__(256) void k_agg2(const float* __restrict__ xw2, const int* __restrict__ rowptr,
    const int* __restrict__ col, const float* __restrict__ dinv, const float* __restrict__ bg2,
    float* __restrict__ h2) {
  int w = blockIdx.x * 4 + (threadIdx.x >> 6);
  int lane = threadIdx.x & 63;
  int b = w / (NV / 2), p = w - b * (NV / 2);
  int v = p * 2 + (lane >> 5);
  int j2 = lane & 31;
  int r0 = rowptr[v], r1 = rowptr[v + 1];
  const float* base = xw2 + (size_t)b * NV * 32;
  float acc = 0.f;
  for (int i = r0; i < r1; ++i) {
    int u = col[i];
    acc += dinv[u] * base[(size_t)u * 32 + j2];
  }
  acc = acc * dinv[v] + bg2[j2];
  h2[((size_t)b * NV + v) * 32 + j2] = acc > 0.f ? acc : 0.01f * acc;
}
__global__ __launch_bounds__(256) void k_gemm3(const float* __restrict__ h2, const float* __restrict__ Wg3,
    float* __restrict__ xw3) {
  __shared__ float w[96];
  if (threadIdx.x < 96) w[threadIdx.x] = Wg3[threadIdx.x];
  __syncthreads();
  int row = blockIdx.x * 256 + threadIdx.x;
  if (row >= BATCH * NV) return;
  const float* hr = h2 + (size_t)row * 32;
  float a0 = 0, a1 = 0, a2 = 0;
  #pragma unroll
  for (int j = 0; j < 32; ++j) {
    float hv = hr[j];
    a0 += hv * w[j * 3 + 0];
    a1 += hv * w[j * 3 + 1];
    a2 += hv * w[j * 3 + 2];
  }
  float4 o; o.x = a0; o.y = a1; o.z = a2; o.w = 0.f;
  *(float4*)(xw3 + (size_t)row * 4) = o;
}
__global__ __launch_bounds__(256) void k_agg3(const float* __restrict__ xw3, const int* __restrict__ rowptr,
    const int* __restrict__ col, const float* __restrict__ dinv, const float* __restrict__ bg3,
    float* __restrict__ out) {
  int t = blockIdx.x * 256 + threadIdx.x;
  if (t >= BATCH * NV) return;
  int b = t / NV, v = t - b * NV;
  int r0 = rowptr[v], r1 = rowptr[v + 1];
  const float* base = xw3 + (size_t)b * NV * 4;
  float a0 = 0, a1 = 0, a2 = 0;
  for (int i = r0; i < r1; ++i) {
    int u = col[i];
    float wt = dinv[u];
    float4 x = *(const float4*)(base + (size_t)u * 4);
    a0 += wt * x.x; a1 += wt * x.y; a2 += wt * x.z;
  }
  float dv = dinv[v];
  float* o = out + (size_t)t * 4;
  o[0] = a0 * dv + bg3[0];
  o[1] = a1 * dv + bg3[1];
  o[2] = a2 * dv + bg3[2];
}

extern "C" void kernel_launch(void* const* d_in, const int* in_sizes, int n_in,
                              void* d_out, int out_size, void* d_ws, size_t ws_size,
                              hipStream_t stream) {
  const float* img = (const float*)d_in[0];
  const int*   ei  = (const int*)d_in[1];
  const float* Wx  = (const float*)d_in[2];
  const float* bx  = (const float*)d_in[3];
  const float* Wy  = (const float*)d_in[4];
  const float* by  = (const float*)d_in[5];
  const float* Wz1 = (const float*)d_in[6];
  const float* bz1 = (const float*)d_in[7];
  const float* Wz2 = (const float*)d_in[8];
  const float* bz2 = (const float*)d_in[9];
  const float* Ww1 = (const float*)d_in[10];
  const float* bw1 = (const float*)d_in[11];
  const float* Ww2 = (const float*)d_in[12];
  const float* bw2 = (const float*)d_in[13];
  const float* Wg1 = (const float*)d_in[14];
  const float* bg1 = (const float*)d_in[15];
  const float* Wg2 = (const float*)d_in[16];
  const float* bg2 = (const float*)d_in[17];
  const float* Wg3 = (const float*)d_in[18];
  const float* bg3 = (const float*)d_in[19];
  float* out = (float*)d_out;
  int E = in_sizes[1] / 2;

  char* ws = (char*)d_ws;
  float*          U      = (float*)(ws + 0ULL);            // 56,442,880  [b][v][64]
  float*          h1     = (float*)(ws + 56442880ULL);     // 56,442,880
  __hip_bfloat16* Wcatb  = (__hip_bfloat16*)(ws + 112885760ULL); // 23,003,136 [6912][1664]
  float*          P      = (float*)(ws + 135888896ULL);    // 13,631,488  [1664][2048]
  __hip_bfloat16* PT     = (__hip_bfloat16*)(ws + 149520384ULL); // 6,815,744 [2048][1664]
  float*          mx     = (float*)(ws + 156336128ULL);    //  5,160,960
  float*          my     = (float*)(ws + 161497088ULL);    //  5,160,960
  float*          Z1T    = (float*)(ws + 166658048ULL);    //  1,605,632
  float*          W1T    = (float*)(ws + 168263680ULL);    //  1,605,632
  float*          gT     = (float*)(ws + 169869312ULL);    //     92,160
  float*          w1m    = (float*)(ws + 169961472ULL);    //     28,672
  float*          S      = (float*)(ws + 169990144ULL);    //      1,024
  float*          deg    = (float*)(ws + 169991168ULL);
  float*          dinv   = (float*)(ws + 170018816ULL);
  int*            rowptr = (int*)(ws + 170046464ULL);
  int*            cursor = (int*)(ws + 170074112ULL);
  int*            colx   = (int*)(ws + 170101760ULL);      //    196,608
  float* xw2 = (float*)(ws + 112885760ULL);  // alias Wcatb+P (dead after gemm), 28.2 MB < 36.6 MB
  float* h2  = U;                            // alias: U dead after k_agg1
  float* xw3 = (float*)(ws + 149520384ULL);  // alias PT (dead after gemm), 3.5 MB < 6.8 MB

  // graph prep
  k_deg_init<<<(NV + 255) / 256, 256, 0, stream>>>(deg);
  k_deg_count<<<(E + 255) / 256, 256, 0, stream>>>(ei, deg, E);
  k_dinv<<<(NV + 255) / 256, 256, 0, stream>>>(deg, dinv);
  k_scan<<<1, 1024, 0, stream>>>(deg, rowptr, cursor);
  k_fill<<<(E + NV + 255) / 256, 256, 0, stream>>>(ei, rowptr, cursor, colx, E);

  // heads
  k_img_reduce<<<BATCH * C720, 64, 0, stream>>>(img, mx, my, gT);
  k_head1<<<dim3(12544 / 8, 2), 256, 0, stream>>>(Wz1, bz1, Ww1, bw1, gT, Z1T, W1T);
  k_w1m<<<(224 * 32 + 255) / 256, 256, 0, stream>>>(W1T, w1m);
  k_coordw<<<(NV + 7) / 8, 256, 0, stream>>>(Ww2, bw2, w1m, out);
  k_S<<<1, 64, 0, stream>>>(Wg1, S);
  k_passem<<<dim3(KBIG, BATCH), 64, 0, stream>>>(mx, my, Z1T, Wg1, P);
  k_transp<<<dim3(KBIG / 64, NBIG / 64), 256, 0, stream>>>(P, PT);
  k_wcat<<<dim3(7, MPAD), 256, 0, stream>>>(Wx, Wy, Wz2, Wcatb);
  k_mfma_gemm<<<dim3(MPAD / 128, NBIG / 128), 256, 0, stream>>>(Wcatb, PT, bx, by, bz2, S, U);

  // GCN
  k_agg1<<<BATCH * NV / 4, 256, 0, stream>>>(U, rowptr, colx, dinv, bg1, h1);
  k_gemm2<<<BATCH * NV / 8, 256, 0, stream>>>(h1, Wg2, xw2);
  k_agg2<<<BATCH * (NV / 2) / 4, 256, 0, stream>>>(xw2, rowptr, colx, dinv, bg2, h2);
  k_gemm3<<<(BATCH * NV + 255) / 256, 256, 0, stream>>>(h2, Wg3, xw3);
  k_agg3<<<(BATCH * NV + 255) / 256, 256, 0, stream>>>(xw3, rowptr, colx, dinv, bg3, out);
}

// Round 3
// 723.666 us; speedup vs baseline: 1.8441x; 1.1038x over previous
//
#include <hip/hip_runtime.h>
#include <hip/hip_bf16.h>
#include <math.h>

#define NV 6890
#define BATCH 32
#define C720 720
#define HW 56
#define KBIG 1664
#define NBIG 2048
#define MPAD 6912

typedef __attribute__((ext_vector_type(8))) short bf16x8;
typedef __attribute__((ext_vector_type(4))) float f32x4;

__device__ inline void gload16(const void* g, void* l) {
  __builtin_amdgcn_global_load_lds((const __attribute__((address_space(1))) void*)g,
                                   (__attribute__((address_space(3))) void*)l, 16, 0, 0);
}
__device__ inline float bf2f(short s) {
  union { unsigned u; float f; } c; c.u = ((unsigned)(unsigned short)s) << 16; return c.f;
}

// ---------- K1: img_feat [B,720,56,56] -> mx (mean over h), my (mean over w), gT[c][b]
// wave-per-tile, LDS-staged, coalesced float4 loads (1KB/wave-instr), pad-57 rows.
__global__ __launch_bounds__(256) void k_img_reduce(const float* __restrict__ img,
    float* __restrict__ mx, float* __restrict__ my, float* __restrict__ gT) {
  __shared__ float lds[4][56 * 57];
  const int wid = threadIdx.x >> 6, lane = threadIdx.x & 63;
  const int t0 = blockIdx.x * 4 + wid;            // tile = b*720+c
  const int b = t0 / C720, c = t0 - b * C720;
  const float4* tp4 = (const float4*)(img + (size_t)t0 * (HW * HW));
  float* L = lds[wid];
  #pragma unroll
  for (int i = 0; i < 12; ++i) {
    int idx = i * 64 + lane;                      // float4 index, 784 total
    float4 v = tp4[idx];
    int h = idx / 14, wq = idx - h * 14;
    float* d = &L[h * 57 + wq * 4];
    d[0] = v.x; d[1] = v.y; d[2] = v.z; d[3] = v.w;
  }
  if (lane < 16) {
    int idx = 768 + lane;
    float4 v = tp4[idx];
    int h = idx / 14, wq = idx - h * 14;
    float* d = &L[h * 57 + wq * 4];
    d[0] = v.x; d[1] = v.y; d[2] = v.z; d[3] = v.w;
  }
  __syncthreads();
  float cs = 0.f, rs = 0.f;
  if (lane < HW) {
    #pragma unroll 8
    for (int h = 0; h < HW; ++h) cs += L[h * 57 + lane];     // column sum (2-way max)
    #pragma unroll 8
    for (int w = 0; w < HW; ++w) rs += L[lane * 57 + w];     // row sum (2-way max)
    mx[(size_t)t0 * HW + lane] = cs * (1.f / HW);
    my[(size_t)t0 * HW + lane] = rs * (1.f / HW);
  }
  float tot = (lane < HW) ? cs : 0.f;
  #pragma unroll
  for (int off = 32; off > 0; off >>= 1) tot += __shfl_down(tot, off);
  if (lane == 0) gT[c * BATCH + b] = tot * (1.f / (HW * HW));
}

// ---------- K2: Z1T/W1T [r][b] = sum_k W[r,k]*g[b,k] + bias[r]
__global__ __launch_bounds__(256) void k_head1(const float* __restrict__ Wz1, const float* __restrict__ bz1,
    const float* __restrict__ Ww1, const float* __restrict__ bw1,
    const float* __restrict__ gT, float* __restrict__ Z1T, float* __restrict__ W1T) {
  int r = blockIdx.x * 8 + (threadIdx.x >> 5);
  int b = threadIdx.x & 31;
  const float* W = blockIdx.y ? Ww1 : Wz1;
  const float* bias = blockIdx.y ? bw1 : bz1;
  float* out = blockIdx.y ? W1T : Z1T;
  const float* wr = W + (size_t)r * C720;
  float acc = 0.f;
  for (int k = 0; k < C720; k += 4) {
    float4 wv = *(const float4*)(wr + k);
    acc += wv.x * gT[(k    ) * 32 + b];
    acc += wv.y * gT[(k + 1) * 32 + b];
    acc += wv.z * gT[(k + 2) * 32 + b];
    acc += wv.w * gT[(k + 3) * 32 + b];
  }
  out[r * 32 + b] = acc + bias[r];
}

// ---------- K3: w1m[c][b] = mean_l W1T[(c*56+l)][b]
__global__ __launch_bounds__(256) void k_w1m(const float* __restrict__ W1T, float* __restrict__ w1m) {
  int t = blockIdx.x * 256 + threadIdx.x;
  if (t >= 224 * 32) return;
  int c = t >> 5, b = t & 31;
  float s = 0.f;
  for (int l = 0; l < HW; ++l) s += W1T[(c * HW + l) * 32 + b];
  w1m[t] = s * (1.f / HW);
}

// ---------- K4: coord_w -> out[...,3]
__global__ __launch_bounds__(256) void k_coordw(const float* __restrict__ Ww2, const float* __restrict__ bw2,
    const float* __restrict__ w1m, float* __restrict__ out) {
  int v = blockIdx.x * 8 + (threadIdx.x >> 5);
  int b = threadIdx.x & 31;
  if (v >= NV) return;
  const float* wr = Ww2 + (size_t)v * 224;
  float acc = 0.f;
  for (int c = 0; c < 224; c += 4) {
    float4 wv = *(const float4*)(wr + c);
    acc += wv.x * w1m[(c    ) * 32 + b];
    acc += wv.y * w1m[(c + 1) * 32 + b];
    acc += wv.z * w1m[(c + 2) * 32 + b];
    acc += wv.w * w1m[(c + 3) * 32 + b];
  }
  acc += bw2[v];
  out[((size_t)b * NV + v) * 4 + 3] = 1.f / (1.f + expf(-acc));
}

// ---------- K5: S[3][64] column sums of Wg1 blocks
__global__ void k_S(const float* __restrict__ Wg1, float* __restrict__ S) {
  int j = threadIdx.x;
  float s0 = 0, s1 = 0, s2 = 0;
  for (int l = 0; l < HW; ++l) {
    s0 += Wg1[l * 64 + j];
    s1 += Wg1[(HW + l) * 64 + j];
    s2 += Wg1[(112 + l) * 64 + j];
  }
  S[j] = s0; S[64 + j] = s1; S[128 + j] = s2;
}

// ---------- K6: P[cp][b*64+j]  (fp32, N-major)
__global__ __launch_bounds__(64) void k_passem(const float* __restrict__ mx, const float* __restrict__ my,
    const float* __restrict__ Z1T, const float* __restrict__ Wg1, float* __restrict__ P) {
  int cp = blockIdx.x, b = blockIdx.y, j = threadIdx.x;
  float acc = 0.f;
  if (cp < 720) {
    const float* x = mx + ((size_t)b * C720 + cp) * HW;
    for (int l = 0; l < HW; ++l) acc += x[l] * Wg1[l * 64 + j];
  } else if (cp < 1440) {
    const float* x = my + ((size_t)b * C720 + (cp - 720)) * HW;
    for (int l = 0; l < HW; ++l) acc += x[l] * Wg1[(HW + l) * 64 + j];
  } else {
    int c = cp - 1440;
    for (int l = 0; l < HW; ++l) acc += Z1T[(c * HW + l) * 32 + b] * Wg1[(112 + l) * 64 + j];
  }
  P[(size_t)cp * NBIG + b * 64 + j] = acc;
}

// ---------- K6b: transpose-convert P[k][n] fp32 -> PT[n][k] bf16
__global__ __launch_bounds__(256) void k_transp(const float* __restrict__ P, __hip_bfloat16* __restrict__ PT) {
  __shared__ __hip_bfloat16 t[64][66];
  int k0 = blockIdx.x * 64, n0 = blockIdx.y * 64;
  int tx = threadIdx.x & 63, ty4 = threadIdx.x >> 6;
  #pragma unroll
  for (int i = 0; i < 16; ++i) {
    int k = ty4 * 16 + i;
    t[k][tx] = (__hip_bfloat16)P[(size_t)(k0 + k) * NBIG + n0 + tx];
  }
  __syncthreads();
  #pragma unroll
  for (int i = 0; i < 16; ++i) {
    int n = ty4 * 16 + i;
    PT[(size_t)(n0 + n) * KBIG + k0 + tx] = t[tx][n];
  }
}

// ---------- K7: Wcatb [6912][1664] bf16 = [Wx | Wy | Wz2]
__global__ __launch_bounds__(256) void k_wcat(const float* __restrict__ Wx, const float* __restrict__ Wy,
    const float* __restrict__ Wz2, __hip_bfloat16* __restrict__ Wcatb) {
  int c = blockIdx.x * 256 + threadIdx.x;
  int v = blockIdx.y;
  if (c >= KBIG) return;
  float val = 0.f;
  if (v < NV) {
    if (c < 720)       val = Wx[(size_t)v * 720 + c];
    else if (c < 1440) val = Wy[(size_t)v * 720 + (c - 720)];
    else               val = Wz2[(size_t)v * 224 + (c - 1440)];
  }
  Wcatb[(size_t)v * KBIG + c] = (__hip_bfloat16)val;
}

// ---------- K8: bf16 MFMA GEMM (m97 structure, XCD-swizzled), bf16 U out
__global__ __launch_bounds__(256) void k_mfma_gemm(
    const __hip_bfloat16* __restrict__ A, const __hip_bfloat16* __restrict__ BT,
    const float* __restrict__ bx, const float* __restrict__ by, const float* __restrict__ bz2,
    const float* __restrict__ S, __hip_bfloat16* __restrict__ U) {
  __shared__ __hip_bfloat16 As[128 * 64];
  __shared__ __hip_bfloat16 Bs[128 * 64];
  const int tid = threadIdx.x;
  const int wid = tid >> 6, lane = tid & 63;
  // XCD-aware bijective swizzle: 864 blocks, 8 XCDs, 108 per XCD
  const int orig = blockIdx.y * gridDim.x + blockIdx.x;
  const int swz = (orig & 7) * 108 + (orig >> 3);
  const int bxid = swz % (MPAD / 128), byid = swz / (MPAD / 128);
  const int m0 = bxid * 128, n0 = byid * 128;
  const int wr = wid >> 1, wc = wid & 1;
  const int l15 = lane & 15, lhi = lane >> 4;
  const int lk = lhi * 8;

  f32x4 acc[4][4];
  #pragma unroll
  for (int i = 0; i < 4; ++i)
    #pragma unroll
    for (int j = 0; j < 4; ++j) acc[i][j] = (f32x4){0.f, 0.f, 0.f, 0.f};

  const __hip_bfloat16* ag = A  + (size_t)(m0 + (tid >> 3)) * KBIG + (tid & 7) * 8;
  const __hip_bfloat16* bg = BT + (size_t)(n0 + (tid >> 3)) * KBIG + (tid & 7) * 8;
  const int lbase = wid * 512;

  for (int kt = 0; kt < KBIG; kt += 64) {
    #pragma unroll
    for (int p = 0; p < 4; ++p) {
      gload16(ag + kt + (size_t)(p * 32) * KBIG, (void*)&As[p * 2048 + lbase]);
      gload16(bg + kt + (size_t)(p * 32) * KBIG, (void*)&Bs[p * 2048 + lbase]);
    }
    __syncthreads();
    #pragma unroll
    for (int ks = 0; ks < 2; ++ks) {
      bf16x8 af[4], bf[4];
      #pragma unroll
      for (int mf = 0; mf < 4; ++mf)
        af[mf] = *(const bf16x8*)&As[(wr * 64 + mf * 16 + l15) * 64 + ks * 32 + lk];
      #pragma unroll
      for (int nf = 0; nf < 4; ++nf)
        bf[nf] = *(const bf16x8*)&Bs[(wc * 64 + nf * 16 + l15) * 64 + ks * 32 + lk];
      #pragma unroll
      for (int mf = 0; mf < 4; ++mf)
        #pragma unroll
        for (int nf = 0; nf < 4; ++nf)
          acc[mf][nf] = __builtin_amdgcn_mfma_f32_16x16x32_bf16(af[mf], bf[nf], acc[mf][nf], 0, 0, 0);
    }
    __syncthreads();
  }

  float s0[4], s1[4], s2[4];
  #pragma unroll
  for (int nf = 0; nf < 4; ++nf) {
    int jj = nf * 16 + l15;
    s0[nf] = S[jj]; s1[nf] = S[64 + jj]; s2[nf] = S[128 + jj];
  }
  __hip_bfloat16* Ub = U + (size_t)((n0 >> 6) + wc) * NV * 64;
  #pragma unroll
  for (int mf = 0; mf < 4; ++mf) {
    #pragma unroll
    for (int r = 0; r < 4; ++r) {
      int v = m0 + wr * 64 + mf * 16 + lhi * 4 + r;
      if (v >= NV) continue;
      float bxv = bx[v], byv = by[v], bzv = bz2[v];
      #pragma unroll
      for (int nf = 0; nf < 4; ++nf) {
        int jj = nf * 16 + l15;
        Ub[(size_t)v * 64 + jj] = (__hip_bfloat16)(acc[mf][nf][r] + bxv * s0[nf] + byv * s1[nf] + bzv * s2[nf]);
      }
    }
  }
}

// ---------- graph prep
__global__ __launch_bounds__(256) void k_deg_init(float* deg) {
  int v = blockIdx.x * 256 + threadIdx.x;
  if (v < NV) deg[v] = 1.f;
}
__global__ __launch_bounds__(256) void k_deg_count(const int* __restrict__ ei, float* deg, int E) {
  int e = blockIdx.x * 256 + threadIdx.x;
  if (e < E) atomicAdd(&deg[ei[E + e]], 1.f);
}
__global__ __launch_bounds__(1024) void k_scan(const float* __restrict__ deg, int* rowptr, int* cursor,
    float* __restrict__ dinv) {
  __shared__ int sdata[1024];
  const int PER = 7;
  int tid = threadIdx.x;
  int base = tid * PER;
  int loc[PER]; int tot = 0;
  for (int i = 0; i < PER; ++i) {
    int idx = base + i;
    int cnt = (idx < NV) ? (int)deg[idx] : 0;
    loc[i] = tot; tot += cnt;
  }
  sdata[tid] = tot; __syncthreads();
  for (int off = 1; off < 1024; off <<= 1) {
    int vcur = sdata[tid];
    int add = (tid >= off) ? sdata[tid - off] : 0;
    __syncthreads();
    sdata[tid] = vcur + add;
    __syncthreads();
  }
  int excl = sdata[tid] - tot;
  for (int i = 0; i < PER; ++i) {
    int idx = base + i;
    if (idx < NV) {
      rowptr[idx] = excl + loc[i]; cursor[idx] = 0;
      dinv[idx] = rsqrtf(deg[idx]);
    }
  }
  if (tid == 1023) rowptr[NV] = sdata[1023];
}
__global__ __launch_bounds__(256) void k_fill(const int* __restrict__ ei, const int* __restrict__ rowptr,
    int* cursor, int* col, int E) {
  int i = blockIdx.x * 256 + threadIdx.x;
  int N = E + NV;
  if (i >= N) return;
  int s, d;
  if (i < E) { s = ei[i]; d = ei[E + i]; } else { s = d = i - E; }
  int pos = atomicAdd(&cursor[d], 1);
  col[rowptr[d] + pos] = s;
}

// ---------- GCN layers (bf16 intermediates, fp32 math)
__global__ __launch_bounds__(256) void k_agg1(const __hip_bfloat16* __restrict__ U, const int* __restrict__ rowptr,
    const int* __restrict__ col, const float* __restrict__ dinv, const float* __restrict__ bg1,
    __hip_bfloat16* __restrict__ h1) {
  int w = blockIdx.x * 4 + (threadIdx.x >> 6);
  int lane = threadIdx.x & 63;
  int b = w / NV, v = w - b * NV;
  int r0 = rowptr[v], r1 = rowptr[v + 1];
  const __hip_bfloat16* base = U + (size_t)b * NV * 64;
  float acc = 0.f;
  for (int i = r0; i < r1; ++i) {
    int u = col[i];
    acc += dinv[u] * __bfloat162float(base[(size_t)u * 64 + lane]);
  }
  acc = acc * dinv[v] + bg1[lane];
  h1[((size_t)b * NV + v) * 64 + lane] = (__hip_bfloat16)(acc > 0.f ? acc : 0.01f * acc);
}
__global__ __launch_bounds__(256) void k_gemm2(const __hip_bfloat16* __restrict__ h1, const float* __restrict__ Wg2,
    __hip_bfloat16* __restrict__ xw2) {
  __shared__ float w[64 * 32];
  for (int i = threadIdx.x; i < 2048; i += 256) w[i] = Wg2[i];
  __syncthreads();
  int row = blockIdx.x * 8 + (threadIdx.x >> 5);
  int j2 = threadIdx.x & 31;
  const bf16x8* hr = (const bf16x8*)(h1 + (size_t)row * 64);
  float acc = 0.f;
  #pragma unroll
  for (int q = 0; q < 8; ++q) {
    bf16x8 hv = hr[q];
    #pragma unroll
    for (int e = 0; e < 8; ++e) acc += bf2f(hv[e]) * w[(q * 8 + e) * 32 + j2];
  }
  xw2[(size_t)row * 32 + j2] = (__hip_bfloat16)acc;
}
__global__ __launch_bounds__(256) void k_agg2(const __hip_bfloat16* __restrict__ xw2, const int* __restrict__ rowptr,
    const int* __restrict__ col, const float* __restrict__ dinv, const float* __restrict__ bg2,
    __hip_bfloat16* __restrict__ h2) {
  int w = blockIdx.x * 4 + (threadIdx.x >> 6);
  int lane = threadIdx.x & 63;
  int b = w / (NV / 2), p = w - b * (NV / 2);
  int v = p * 2 + (lane >> 5);
  int j2 = lane & 31;
  int r0 = rowptr[v], r1 = rowptr[v + 1];
  const __hip_bfloat16* base = xw2 + (size_t)b * NV * 32;
  float acc = 0.f;
  for (int i = r0; i < r1; ++i) {
    int u = col[i];
    acc += dinv[u] * __bfloat162float(base[(size_t)u * 32 + j2]);
  }
  acc = acc * dinv[v] + bg2[j2];
  h2[((size_t)b * NV + v) * 32 + j2] = (__hip_bfloat16)(acc > 0.f ? acc : 0.01f * acc);
}
__global__ __launch_bounds__(256) void k_gemm3(const __hip_bfloat16* __restrict__ h2, const float* __restrict__ Wg3,
    float* __restrict__ xw3) {
  __shared__ float w[96];
  if (threadIdx.x < 96) w[threadIdx.x] = Wg3[threadIdx.x];
  __syncthreads();
  int row = blockIdx.x * 256 + threadIdx.x;
  if (row >= BATCH * NV) return;
  const bf16x8* hr = (const bf16x8*)(h2 + (size_t)row * 32);
  float a0 = 0, a1 = 0, a2 = 0;
  #pragma unroll
  for (int q = 0; q < 4; ++q) {
    bf16x8 hv = hr[q];
    #pragma unroll
    for (int e = 0; e < 8; ++e) {
      float f = bf2f(hv[e]);
      a0 += f * w[(q * 8 + e) * 3 + 0];
      a1 += f * w[(q * 8 + e) * 3 + 1];
      a2 += f * w[(q * 8 + e) * 3 + 2];
    }
  }
  float4 o; o.x = a0; o.y = a1; o.z = a2; o.w = 0.f;
  *(float4*)(xw3 + (size_t)row * 4) = o;
}
__global__ __launch_bounds__(256) void k_agg3(const float* __restrict__ xw3, const int* __restrict__ rowptr,
    const int* __restrict__ col, const float* __restrict__ dinv, const float* __restrict__ bg3,
    float* __restrict__ out) {
  int t = blockIdx.x * 256 + threadIdx.x;
  if (t >= BATCH * NV) return;
  int b = t / NV, v = t - b * NV;
  int r0 = rowptr[v], r1 = rowptr[v + 1];
  const float* base = xw3 + (size_t)b * NV * 4;
  float a0 = 0, a1 = 0, a2 = 0;
  for (int i = r0; i < r1; ++i) {
    int u = col[i];
    float wt = dinv[u];
    float4 x = *(const float4*)(base + (size_t)u * 4);
    a0 += wt * x.x; a1 += wt * x.y; a2 += wt * x.z;
  }
  float dv = dinv[v];
  float* o = out + (size_t)t * 4;
  o[0] = a0 * dv + bg3[0];
  o[1] = a1 * dv + bg3[1];
  o[2] = a2 * dv + bg3[2];
}

extern "C" void kernel_launch(void* const* d_in, const int* in_sizes, int n_in,
                              void* d_out, int out_size, void* d_ws, size_t ws_size,
                              hipStream_t stream) {
  const float* img = (const float*)d_in[0];
  const int*   ei  = (const int*)d_in[1];
  const float* Wx  = (const float*)d_in[2];
  const float* bx  = (const float*)d_in[3];
  const float* Wy  = (const float*)d_in[4];
  const float* by  = (const float*)d_in[5];
  const float* Wz1 = (const float*)d_in[6];
  const float* bz1 = (const float*)d_in[7];
  const float* Wz2 = (const float*)d_in[8];
  const float* bz2 = (const float*)d_in[9];
  const float* Ww1 = (const float*)d_in[10];
  const float* bw1 = (const float*)d_in[11];
  const float* Ww2 = (const float*)d_in[12];
  const float* bw2 = (const float*)d_in[13];
  const float* Wg1 = (const float*)d_in[14];
  const float* bg1 = (const float*)d_in[15];
  const float* Wg2 = (const float*)d_in[16];
  const float* bg2 = (const float*)d_in[17];
  const float* Wg3 = (const float*)d_in[18];
  const float* bg3 = (const float*)d_in[19];
  float* out = (float*)d_out;
  int E = in_sizes[1] / 2;

  char* ws = (char*)d_ws;
  __hip_bfloat16* U      = (__hip_bfloat16*)(ws + 0ULL);         // 28,221,440 [b][v][64] bf16
  __hip_bfloat16* h1     = (__hip_bfloat16*)(ws + 56442880ULL);  // 28,221,440 bf16
  __hip_bfloat16* Wcatb  = (__hip_bfloat16*)(ws + 112885760ULL); // 23,003,136 [6912][1664]
  float*          P      = (float*)(ws + 135888896ULL);          // 13,631,488 [1664][2048]
  __hip_bfloat16* PT     = (__hip_bfloat16*)(ws + 149520384ULL); //  6,815,744 [2048][1664]
  float*          mx     = (float*)(ws + 156336128ULL);          //  5,160,960
  float*          my     = (float*)(ws + 161497088ULL);          //  5,160,960
  float*          Z1T    = (float*)(ws + 166658048ULL);          //  1,605,632
  float*          W1T    = (float*)(ws + 168263680ULL);          //  1,605,632
  float*          gT     = (float*)(ws + 169869312ULL);          //     92,160
  float*          w1m    = (float*)(ws + 169961472ULL);          //     28,672
  float*          S      = (float*)(ws + 169990144ULL);          //      1,024
  float*          deg    = (float*)(ws + 169991168ULL);
  float*          dinv   = (float*)(ws + 170018816ULL);
  int*            rowptr = (int*)(ws + 170046464ULL);
  int*            cursor = (int*)(ws + 170074112ULL);
  int*            colx   = (int*)(ws + 170101760ULL);            //    196,608
  __hip_bfloat16* xw2 = (__hip_bfloat16*)(ws + 112885760ULL);    // alias Wcatb (dead after gemm)
  __hip_bfloat16* h2  = U;                                       // alias: U dead after k_agg1
  float*          xw3 = (float*)(ws + 149520384ULL);             // alias PT (dead after gemm)

  // graph prep
  k_deg_init<<<(NV + 255) / 256, 256, 0, stream>>>(deg);
  k_deg_count<<<(E + 255) / 256, 256, 0, stream>>>(ei, deg, E);
  k_scan<<<1, 1024, 0, stream>>>(deg, rowptr, cursor, dinv);
  k_fill<<<(E + NV + 255) / 256, 256, 0, stream>>>(ei, rowptr, cursor, colx, E);

  // heads
  k_img_reduce<<<BATCH * C720 / 4, 256, 0, stream>>>(img, mx, my, gT);
  k_head1<<<dim3(12544 / 8, 2), 256, 0, stream>>>(Wz1, bz1, Ww1, bw1, gT, Z1T, W1T);
  k_w1m<<<(224 * 32 + 255) / 256, 256, 0, stream>>>(W1T, w1m);
  k_coordw<<<(NV + 7) / 8, 256, 0, stream>>>(Ww2, bw2, w1m, out);
  k_S<<<1, 64, 0, stream>>>(Wg1, S);
  k_passem<<<dim3(KBIG, BATCH), 64, 0, stream>>>(mx, my, Z1T, Wg1, P);
  k_transp<<<dim3(KBIG / 64, NBIG / 64), 256, 0, stream>>>(P, PT);
  k_wcat<<<dim3(7, MPAD), 256, 0, stream>>>(Wx, Wy, Wz2, Wcatb);
  k_mfma_gemm<<<dim3(MPAD / 128, NBIG / 128), 256, 0, stream>>>(Wcatb, PT, bx, by, bz2, S, U);

  // GCN
  k_agg1<<<BATCH * NV / 4, 256, 0, stream>>>(U, rowptr, colx, dinv, bg1, h1);
  k_gemm2<<<BATCH * NV / 8, 256, 0, stream>>>(h1, Wg2, xw2);
  k_agg2<<<BATCH * (NV / 2) / 4, 256, 0, stream>>>(xw2, rowptr, colx, dinv, bg2, h2);
  k_gemm3<<<(BATCH * NV + 255) / 256, 256, 0, stream>>>(h2, Wg3, xw3);
  k_agg3<<<(BATCH * NV + 255) / 256, 256, 0, stream>>>(xw3, rowptr, colx, dinv, bg3, out);
}

// Round 4
// 661.107 us; speedup vs baseline: 2.0186x; 1.0946x over previous
//
#include <hip/hip_runtime.h>
#include <hip/hip_bf16.h>
#include <math.h>

#define NV 6890
#define BATCH 32
#define C720 720
#define HW 56
#define KBIG 1664
#define K2 1728          // augmented K (1664 + 3 bias cols + pad), multiple of 64
#define NBIG 2048
#define MPAD 6912

typedef __attribute__((ext_vector_type(8))) short bf16x8;
typedef __attribute__((ext_vector_type(4))) float f32x4;

__device__ inline void gload16(const void* g, void* l) {
  __builtin_amdgcn_global_load_lds((const __attribute__((address_space(1))) void*)g,
                                   (__attribute__((address_space(3))) void*)l, 16, 0, 0);
}
__device__ inline float bf2f(short s) {
  union { unsigned u; float f; } c; c.u = ((unsigned)(unsigned short)s) << 16; return c.f;
}

// ---------- K0: single-block graph prep (deg -> dinv, rowptr scan, CSR fill) + S sums
__global__ __launch_bounds__(1024) void k_prep(const int* __restrict__ ei, int E,
    const float* __restrict__ Wg1, float* __restrict__ S,
    int* __restrict__ rowptr, float* __restrict__ dinv, int* __restrict__ colx) {
  __shared__ int ldeg[NV];
  __shared__ int lrow[NV];
  __shared__ int sdata[1024];
  const int tid = threadIdx.x;
  if (tid < 64) {
    float s0 = 0, s1 = 0, s2 = 0;
    for (int l = 0; l < HW; ++l) {
      s0 += Wg1[l * 64 + tid];
      s1 += Wg1[(HW + l) * 64 + tid];
      s2 += Wg1[(112 + l) * 64 + tid];
    }
    S[tid] = s0; S[64 + tid] = s1; S[128 + tid] = s2;
  }
  for (int v = tid; v < NV; v += 1024) ldeg[v] = 1;   // self-loop
  __syncthreads();
  for (int e = tid; e < E; e += 1024) atomicAdd(&ldeg[ei[E + e]], 1);
  __syncthreads();
  const int PER = 7;                                   // 1024*7 >= 6890
  int base = tid * PER, loc[PER], tot = 0;
  for (int i = 0; i < PER; ++i) {
    int idx = base + i;
    int c = (idx < NV) ? ldeg[idx] : 0;
    loc[i] = tot; tot += c;
    if (idx < NV) dinv[idx] = rsqrtf((float)c);
  }
  sdata[tid] = tot; __syncthreads();
  for (int off = 1; off < 1024; off <<= 1) {
    int v = sdata[tid];
    int a = (tid >= off) ? sdata[tid - off] : 0;
    __syncthreads();
    sdata[tid] = v + a;
    __syncthreads();
  }
  int excl = sdata[tid] - tot;
  for (int i = 0; i < PER; ++i) {
    int idx = base + i;
    if (idx < NV) { int r = excl + loc[i]; lrow[idx] = r; rowptr[idx] = r; }
  }
  if (tid == 1023) rowptr[NV] = sdata[1023];
  __syncthreads();
  for (int v = tid; v < NV; v += 1024) ldeg[v] = 0;    // reuse as cursor
  __syncthreads();
  int N = E + NV;
  for (int i = tid; i < N; i += 1024) {
    int s, d;
    if (i < E) { s = ei[i]; d = ei[E + i]; } else { s = d = i - E; }
    int pos = atomicAdd(&ldeg[d], 1);
    colx[lrow[d] + pos] = s;
  }
}

// ---------- K1: img_feat -> P rows [0,1440) (x/y heads contracted with Wg1) + gT
__global__ __launch_bounds__(256) void k_img_reduce(const float* __restrict__ img,
    const float* __restrict__ Wg1, float* __restrict__ P, float* __restrict__ gT) {
  __shared__ float lds[4][56 * 57];
  __shared__ float cr[4][2][56];
  const int wid = threadIdx.x >> 6, lane = threadIdx.x & 63;
  const int t0 = blockIdx.x * 4 + wid;            // tile = b*720+c
  const int b = t0 / C720, c = t0 - b * C720;
  const float4* tp4 = (const float4*)(img + (size_t)t0 * (HW * HW));
  float* L = lds[wid];
  #pragma unroll
  for (int i = 0; i < 12; ++i) {
    int idx = i * 64 + lane;                      // 784 float4 total
    float4 v = tp4[idx];
    int h = idx / 14, wq = idx - h * 14;
    float* d = &L[h * 57 + wq * 4];
    d[0] = v.x; d[1] = v.y; d[2] = v.z; d[3] = v.w;
  }
  if (lane < 16) {
    int idx = 768 + lane;
    float4 v = tp4[idx];
    int h = idx / 14, wq = idx - h * 14;
    float* d = &L[h * 57 + wq * 4];
    d[0] = v.x; d[1] = v.y; d[2] = v.z; d[3] = v.w;
  }
  __syncthreads();
  float cs = 0.f, rs = 0.f;
  if (lane < HW) {
    #pragma unroll 8
    for (int h = 0; h < HW; ++h) cs += L[h * 57 + lane];     // mean over h (axis2)
    #pragma unroll 8
    for (int w = 0; w < HW; ++w) rs += L[lane * 57 + w];     // mean over w (axis3)
    cr[wid][0][lane] = cs * (1.f / HW);
    cr[wid][1][lane] = rs * (1.f / HW);
  }
  float tot = (lane < HW) ? cs : 0.f;
  #pragma unroll
  for (int off = 32; off > 0; off >>= 1) tot += __shfl_down(tot, off);
  if (lane == 0) gT[c * BATCH + b] = tot * (1.f / (HW * HW));
  // contract with Wg1 (wave-local; LDS written by same wave)
  float ax = 0.f, ay = 0.f;
  #pragma unroll 4
  for (int l = 0; l < HW; ++l) {
    ax += cr[wid][0][l] * Wg1[l * 64 + lane];
    ay += cr[wid][1][l] * Wg1[(HW + l) * 64 + lane];
  }
  P[(size_t)c * NBIG + b * 64 + lane] = ax;
  P[(size_t)(C720 + c) * NBIG + b * 64 + lane] = ay;
}

// ---------- K2: Z1T/W1T [r][b] = sum_k W[r,k]*g[b,k] + bias[r]
__global__ __launch_bounds__(256) void k_head1(const float* __restrict__ Wz1, const float* __restrict__ bz1,
    const float* __restrict__ Ww1, const float* __restrict__ bw1,
    const float* __restrict__ gT, float* __restrict__ Z1T, float* __restrict__ W1T) {
  int r = blockIdx.x * 8 + (threadIdx.x >> 5);
  int b = threadIdx.x & 31;
  const float* W = blockIdx.y ? Ww1 : Wz1;
  const float* bias = blockIdx.y ? bw1 : bz1;
  float* out = blockIdx.y ? W1T : Z1T;
  const float* wr = W + (size_t)r * C720;
  float acc = 0.f;
  for (int k = 0; k < C720; k += 4) {
    float4 wv = *(const float4*)(wr + k);
    acc += wv.x * gT[(k    ) * 32 + b];
    acc += wv.y * gT[(k + 1) * 32 + b];
    acc += wv.z * gT[(k + 2) * 32 + b];
    acc += wv.w * gT[(k + 3) * 32 + b];
  }
  out[r * 32 + b] = acc + bias[r];
}

// ---------- K3: w1m[c][b] = mean_l W1T[(c*56+l)][b]
__global__ __launch_bounds__(256) void k_w1m(const float* __restrict__ W1T, float* __restrict__ w1m) {
  int t = blockIdx.x * 256 + threadIdx.x;
  if (t >= 224 * 32) return;
  int c = t >> 5, b = t & 31;
  float s = 0.f;
  for (int l = 0; l < HW; ++l) s += W1T[(c * HW + l) * 32 + b];
  w1m[t] = s * (1.f / HW);
}

// ---------- K4: coord_w -> out[...,3]
__global__ __launch_bounds__(256) void k_coordw(const float* __restrict__ Ww2, const float* __restrict__ bw2,
    const float* __restrict__ w1m, float* __restrict__ out) {
  int v = blockIdx.x * 8 + (threadIdx.x >> 5);
  int b = threadIdx.x & 31;
  if (v >= NV) return;
  const float* wr = Ww2 + (size_t)v * 224;
  float acc = 0.f;
  for (int c = 0; c < 224; c += 4) {
    float4 wv = *(const float4*)(wr + c);
    acc += wv.x * w1m[(c    ) * 32 + b];
    acc += wv.y * w1m[(c + 1) * 32 + b];
    acc += wv.z * w1m[(c + 2) * 32 + b];
    acc += wv.w * w1m[(c + 3) * 32 + b];
  }
  acc += bw2[v];
  out[((size_t)b * NV + v) * 4 + 3] = 1.f / (1.f + expf(-acc));
}

// ---------- K5: P rows [1440,1664): z-head contracted with Wg1z
__global__ __launch_bounds__(256) void k_passem_z(const float* __restrict__ Z1T,
    const float* __restrict__ Wg1, float* __restrict__ P) {
  __shared__ float Zl[56 * 33];
  __shared__ float Wz[56 * 64];
  const int c = blockIdx.x, tid = threadIdx.x;
  for (int i = tid; i < 1792; i += 256) {
    int l = i >> 5, b = i & 31;
    Zl[l * 33 + b] = Z1T[(size_t)c * 1792 + i];
  }
  for (int i = tid; i < 3584; i += 256) Wz[i] = Wg1[112 * 64 + i];
  __syncthreads();
  int n0 = tid * 8, b = n0 >> 6, j0 = n0 & 63;
  float a[8] = {};
  for (int l = 0; l < HW; ++l) {
    float zv = Zl[l * 33 + b];
    const float* wr = &Wz[l * 64 + j0];
    #pragma unroll
    for (int e = 0; e < 8; ++e) a[e] += zv * wr[e];
  }
  float* dst = P + (size_t)(1440 + c) * NBIG + n0;
  *(float4*)dst = (float4){a[0], a[1], a[2], a[3]};
  *(float4*)(dst + 4) = (float4){a[4], a[5], a[6], a[7]};
}

// ---------- K6: transpose-convert P[k][n] fp32 -> PT[n][k] bf16; k-tile 26 synthesized from S
__global__ __launch_bounds__(256) void k_transp(const float* __restrict__ P, const float* __restrict__ S,
    __hip_bfloat16* __restrict__ PT) {
  __shared__ __hip_bfloat16 t[64][66];
  int k0 = blockIdx.x * 64, n0 = blockIdx.y * 64;
  int tx = threadIdx.x & 63, ty4 = threadIdx.x >> 6;
  if (k0 < KBIG) {
    #pragma unroll
    for (int i = 0; i < 16; ++i) {
      int k = ty4 * 16 + i;
      t[k][tx] = (__hip_bfloat16)P[(size_t)(k0 + k) * NBIG + n0 + tx];
    }
  } else {
    #pragma unroll
    for (int i = 0; i < 16; ++i) {
      int k = ty4 * 16 + i;                       // global row 1664+k
      float v = (k == 0) ? S[tx] : (k == 1) ? S[64 + tx] : (k == 2) ? S[128 + tx] : 0.f;
      t[k][tx] = (__hip_bfloat16)v;
    }
  }
  __syncthreads();
  #pragma unroll
  for (int i = 0; i < 16; ++i) {
    int n = ty4 * 16 + i;
    PT[(size_t)(n0 + n) * K2 + k0 + tx] = t[tx][n];
  }
}

// ---------- K7: Wcatb [6912][1728] bf16 = [Wx | Wy | Wz2 | bx by bz2 0...]
__global__ __launch_bounds__(256) void k_wcat(const float* __restrict__ Wx, const float* __restrict__ Wy,
    const float* __restrict__ Wz2, const float* __restrict__ bx, const float* __restrict__ by,
    const float* __restrict__ bz2, __hip_bfloat16* __restrict__ Wcatb) {
  int idx = blockIdx.x * 256 + threadIdx.x;
  if (idx >= MPAD * (K2 / 8)) return;
  int v = idx / (K2 / 8), c8 = (idx - v * (K2 / 8)) * 8;
  float val[8] = {};
  if (v < NV) {
    if (c8 < 720) {
      const float* s = Wx + (size_t)v * 720 + c8;
      float4 a = *(const float4*)s, b4 = *(const float4*)(s + 4);
      val[0]=a.x; val[1]=a.y; val[2]=a.z; val[3]=a.w; val[4]=b4.x; val[5]=b4.y; val[6]=b4.z; val[7]=b4.w;
    } else if (c8 < 1440) {
      const float* s = Wy + (size_t)v * 720 + (c8 - 720);
      float4 a = *(const float4*)s, b4 = *(const float4*)(s + 4);
      val[0]=a.x; val[1]=a.y; val[2]=a.z; val[3]=a.w; val[4]=b4.x; val[5]=b4.y; val[6]=b4.z; val[7]=b4.w;
    } else if (c8 < 1664) {
      const float* s = Wz2 + (size_t)v * 224 + (c8 - 1440);
      float4 a = *(const float4*)s, b4 = *(const float4*)(s + 4);
      val[0]=a.x; val[1]=a.y; val[2]=a.z; val[3]=a.w; val[4]=b4.x; val[5]=b4.y; val[6]=b4.z; val[7]=b4.w;
    } else if (c8 == 1664) {
      val[0] = bx[v]; val[1] = by[v]; val[2] = bz2[v];
    }
  }
  bf16x8 o;
  #pragma unroll
  for (int e = 0; e < 8; ++e) {
    __hip_bfloat16 h = (__hip_bfloat16)val[e];
    o[e] = *(short*)&h;
  }
  *(bf16x8*)(Wcatb + (size_t)v * K2 + c8) = o;
}

// ---------- K8: Waggb = (A * Wcatb), fp32 accumulation (wave per vertex)
__global__ __launch_bounds__(256) void k_wagg(const __hip_bfloat16* __restrict__ Wcatb,
    const int* __restrict__ rowptr, const int* __restrict__ colx, const float* __restrict__ dinv,
    __hip_bfloat16* __restrict__ Waggb) {
  int w = blockIdx.x * 4 + (threadIdx.x >> 6);
  int lane = threadIdx.x & 63;
  const int i3 = 1536 + lane * 8;
  const bool t3 = i3 < K2;
  __hip_bfloat16* drow = Waggb + (size_t)w * K2;
  if (w >= NV) {                                  // pad rows 6890..6911 -> zero
    if (w < MPAD) {
      bf16x8 z = {};
      *(bf16x8*)(drow + lane * 8) = z;
      *(bf16x8*)(drow + 512 + lane * 8) = z;
      *(bf16x8*)(drow + 1024 + lane * 8) = z;
      if (t3) *(bf16x8*)(drow + i3) = z;
    }
    return;
  }
  int r0 = rowptr[w], r1 = rowptr[w + 1];
  float a0[8] = {}, a1[8] = {}, a2[8] = {}, a3[8] = {};
  for (int i = r0; i < r1; ++i) {
    int u = colx[i];
    float wt = dinv[u];
    const __hip_bfloat16* row = Wcatb + (size_t)u * K2;
    bf16x8 x0 = *(const bf16x8*)(row + lane * 8);
    bf16x8 x1 = *(const bf16x8*)(row + 512 + lane * 8);
    bf16x8 x2 = *(const bf16x8*)(row + 1024 + lane * 8);
    #pragma unroll
    for (int e = 0; e < 8; ++e) {
      a0[e] += wt * bf2f(x0[e]);
      a1[e] += wt * bf2f(x1[e]);
      a2[e] += wt * bf2f(x2[e]);
    }
    if (t3) {
      bf16x8 x3 = *(const bf16x8*)(row + i3);
      #pragma unroll
      for (int e = 0; e < 8; ++e) a3[e] += wt * bf2f(x3[e]);
    }
  }
  float dv = dinv[w];
  bf16x8 o0, o1, o2, o3;
  #pragma unroll
  for (int e = 0; e < 8; ++e) {
    __hip_bfloat16 h0 = (__hip_bfloat16)(a0[e] * dv); o0[e] = *(short*)&h0;
    __hip_bfloat16 h1v = (__hip_bfloat16)(a1[e] * dv); o1[e] = *(short*)&h1v;
    __hip_bfloat16 h2v = (__hip_bfloat16)(a2[e] * dv); o2[e] = *(short*)&h2v;
    __hip_bfloat16 h3 = (__hip_bfloat16)(a3[e] * dv); o3[e] = *(short*)&h3;
  }
  *(bf16x8*)(drow + lane * 8) = o0;
  *(bf16x8*)(drow + 512 + lane * 8) = o1;
  *(bf16x8*)(drow + 1024 + lane * 8) = o2;
  if (t3) *(bf16x8*)(drow + i3) = o3;
}

// ---------- K9: bf16 MFMA GEMM (m97 structure, XCD-swizzled): h1 = leaky(Waggb @ PT^T + bg1)
__global__ __launch_bounds__(256) void k_mfma_gemm(
    const __hip_bfloat16* __restrict__ A, const __hip_bfloat16* __restrict__ BT,
    const float* __restrict__ bg1, __hip_bfloat16* __restrict__ h1) {
  __shared__ __hip_bfloat16 As[128 * 64];
  __shared__ __hip_bfloat16 Bs[128 * 64];
  const int tid = threadIdx.x;
  const int wid = tid >> 6, lane = tid & 63;
  const int orig = blockIdx.y * gridDim.x + blockIdx.x;   // 864 blocks, 108/XCD
  const int swz = (orig & 7) * 108 + (orig >> 3);
  const int bxid = swz % (MPAD / 128), byid = swz / (MPAD / 128);
  const int m0 = bxid * 128, n0 = byid * 128;
  const int wr = wid >> 1, wc = wid & 1;
  const int l15 = lane & 15, lhi = lane >> 4;
  const int lk = lhi * 8;

  f32x4 acc[4][4];
  #pragma unroll
  for (int i = 0; i < 4; ++i)
    #pragma unroll
    for (int j = 0; j < 4; ++j) acc[i][j] = (f32x4){0.f, 0.f, 0.f, 0.f};

  const __hip_bfloat16* ag = A  + (size_t)(m0 + (tid >> 3)) * K2 + (tid & 7) * 8;
  const __hip_bfloat16* bg = BT + (size_t)(n0 + (tid >> 3)) * K2 + (tid & 7) * 8;
  const int lbase = wid * 512;

  for (int kt = 0; kt < K2; kt += 64) {
    #pragma unroll
    for (int p = 0; p < 4; ++p) {
      gload16(ag + kt + (size_t)(p * 32) * K2, (void*)&As[p * 2048 + lbase]);
      gload16(bg + kt + (size_t)(p * 32) * K2, (void*)&Bs[p * 2048 + lbase]);
    }
    __syncthreads();
    #pragma unroll
    for (int ks = 0; ks < 2; ++ks) {
      bf16x8 af[4], bf[4];
      #pragma unroll
      for (int mf = 0; mf < 4; ++mf)
        af[mf] = *(const bf16x8*)&As[(wr * 64 + mf * 16 + l15) * 64 + ks * 32 + lk];
      #pragma unroll
      for (int nf = 0; nf < 4; ++nf)
        bf[nf] = *(const bf16x8*)&Bs[(wc * 64 + nf * 16 + l15) * 64 + ks * 32 + lk];
      #pragma unroll
      for (int mf = 0; mf < 4; ++mf)
        #pragma unroll
        for (int nf = 0; nf < 4; ++nf)
          acc[mf][nf] = __builtin_amdgcn_mfma_f32_16x16x32_bf16(af[mf], bf[nf], acc[mf][nf], 0, 0, 0);
    }
    __syncthreads();
  }

  float bgv[4];
  #pragma unroll
  for (int nf = 0; nf < 4; ++nf) bgv[nf] = bg1[nf * 16 + l15];
  __hip_bfloat16* hb = h1 + (size_t)((n0 >> 6) + wc) * NV * 64;
  #pragma unroll
  for (int mf = 0; mf < 4; ++mf) {
    #pragma unroll
    for (int r = 0; r < 4; ++r) {
      int v = m0 + wr * 64 + mf * 16 + lhi * 4 + r;
      if (v >= NV) continue;
      #pragma unroll
      for (int nf = 0; nf < 4; ++nf) {
        int jj = nf * 16 + l15;
        float x = acc[mf][nf][r] + bgv[nf];
        x = x > 0.f ? x : 0.01f * x;
        hb[(size_t)v * 64 + jj] = (__hip_bfloat16)x;
      }
    }
  }
}

// ---------- GCN tail (bf16 intermediates, fp32 math)
__global__ __launch_bounds__(256) void k_gemm2(const __hip_bfloat16* __restrict__ h1, const float* __restrict__ Wg2,
    __hip_bfloat16* __restrict__ xw2) {
  __shared__ float w[64 * 32];
  for (int i = threadIdx.x; i < 2048; i += 256) w[i] = Wg2[i];
  __syncthreads();
  int row = blockIdx.x * 8 + (threadIdx.x >> 5);
  int j2 = threadIdx.x & 31;
  const bf16x8* hr = (const bf16x8*)(h1 + (size_t)row * 64);
  float acc = 0.f;
  #pragma unroll
  for (int q = 0; q < 8; ++q) {
    bf16x8 hv = hr[q];
    #pragma unroll
    for (int e = 0; e < 8; ++e) acc += bf2f(hv[e]) * w[(q * 8 + e) * 32 + j2];
  }
  xw2[(size_t)row * 32 + j2] = (__hip_bfloat16)acc;
}
__global__ __launch_bounds__(256) void k_agg2(const __hip_bfloat16* __restrict__ xw2, const int* __restrict__ rowptr,
    const int* __restrict__ col, const float* __restrict__ dinv, const float* __restrict__ bg2,
    __hip_bfloat16* __restrict__ h2) {
  int w = blockIdx.x * 4 + (threadIdx.x >> 6);
  int lane = threadIdx.x & 63;
  int b = w / (NV / 2), p = w - b * (NV / 2);
  int v = p * 2 + (lane >> 5);
  int j2 = lane & 31;
  int r0 = rowptr[v], r1 = rowptr[v + 1];
  const __hip_bfloat16* base = xw2 + (size_t)b * NV * 32;
  float acc = 0.f;
  for (int i = r0; i < r1; ++i) {
    int u = col[i];
    acc += dinv[u] * __bfloat162float(base[(size_t)u * 32 + j2]);
  }
  acc = acc * dinv[v] + bg2[j2];
  h2[((size_t)b * NV + v) * 32 + j2] = (__hip_bfloat16)(acc > 0.f ? acc : 0.01f * acc);
}
__global__ __launch_bounds__(256) void k_gemm3(const __hip_bfloat16* __restrict__ h2, const float* __restrict__ Wg3,
    float* __restrict__ xw3) {
  __shared__ float w[96];
  if (threadIdx.x < 96) w[threadIdx.x] = Wg3[threadIdx.x];
  __syncthreads();
  int row = blockIdx.x * 256 + threadIdx.x;
  if (row >= BATCH * NV) return;
  const bf16x8* hr = (const bf16x8*)(h2 + (size_t)row * 32);
  float a0 = 0, a1 = 0, a2 = 0;
  #pragma unroll
  for (int q = 0; q < 4; ++q) {
    bf16x8 hv = hr[q];
    #pragma unroll
    for (int e = 0; e < 8; ++e) {
      float f = bf2f(hv[e]);
      a0 += f * w[(q * 8 + e) * 3 + 0];
      a1 += f * w[(q * 8 + e) * 3 + 1];
      a2 += f * w[(q * 8 + e) * 3 + 2];
    }
  }
  float4 o; o.x = a0; o.y = a1; o.z = a2; o.w = 0.f;
  *(float4*)(xw3 + (size_t)row * 4) = o;
}
__global__ __launch_bounds__(256) void k_agg3(const float* __restrict__ xw3, const int* __restrict__ rowptr,
    const int* __restrict__ col, const float* __restrict__ dinv, const float* __restrict__ bg3,
    float* __restrict__ out) {
  int t = blockIdx.x * 256 + threadIdx.x;
  if (t >= BATCH * NV) return;
  int b = t / NV, v = t - b * NV;
  int r0 = rowptr[v], r1 = rowptr[v + 1];
  const float* base = xw3 + (size_t)b * NV * 4;
  float a0 = 0, a1 = 0, a2 = 0;
  for (int i = r0; i < r1; ++i) {
    int u = col[i];
    float wt = dinv[u];
    float4 x = *(const float4*)(base + (size_t)u * 4);
    a0 += wt * x.x; a1 += wt * x.y; a2 += wt * x.z;
  }
  float dv = dinv[v];
  float* o = out + (size_t)t * 4;
  o[0] = a0 * dv + bg3[0];
  o[1] = a1 * dv + bg3[1];
  o[2] = a2 * dv + bg3[2];
}

extern "C" void kernel_launch(void* const* d_in, const int* in_sizes, int n_in,
                              void* d_out, int out_size, void* d_ws, size_t ws_size,
                              hipStream_t stream) {
  const float* img = (const float*)d_in[0];
  const int*   ei  = (const int*)d_in[1];
  const float* Wx  = (const float*)d_in[2];
  const float* bx  = (const float*)d_in[3];
  const float* Wy  = (const float*)d_in[4];
  const float* by  = (const float*)d_in[5];
  const float* Wz1 = (const float*)d_in[6];
  const float* bz1 = (const float*)d_in[7];
  const float* Wz2 = (const float*)d_in[8];
  const float* bz2 = (const float*)d_in[9];
  const float* Ww1 = (const float*)d_in[10];
  const float* bw1 = (const float*)d_in[11];
  const float* Ww2 = (const float*)d_in[12];
  const float* bw2 = (const float*)d_in[13];
  const float* Wg1 = (const float*)d_in[14];
  const float* bg1 = (const float*)d_in[15];
  const float* Wg2 = (const float*)d_in[16];
  const float* bg2 = (const float*)d_in[17];
  const float* Wg3 = (const float*)d_in[18];
  const float* bg3 = (const float*)d_in[19];
  float* out = (float*)d_out;
  int E = in_sizes[1] / 2;

  char* ws = (char*)d_ws;
  __hip_bfloat16* h1     = (__hip_bfloat16*)(ws + 0ULL);          // 28,221,440 [b][v][64]
  __hip_bfloat16* Wcatb  = (__hip_bfloat16*)(ws + 28221440ULL);   // 23,887,872 [6912][1728]
  __hip_bfloat16* Waggb  = (__hip_bfloat16*)(ws + 52109312ULL);   // 23,887,872 [6912][1728]
  float*          P      = (float*)(ws + 75997184ULL);            // 13,631,488 [1664][2048]
  __hip_bfloat16* PT     = (__hip_bfloat16*)(ws + 89628672ULL);   //  7,077,888 [2048][1728]
  float*          Z1T    = (float*)(ws + 96706560ULL);            //  1,605,632
  float*          W1T    = (float*)(ws + 98312192ULL);            //  1,605,632
  float*          gT     = (float*)(ws + 99917824ULL);            //     92,160
  float*          w1m    = (float*)(ws + 100009984ULL);           //     28,672
  float*          S      = (float*)(ws + 100038656ULL);           //      1,024
  float*          dinv   = (float*)(ws + 100039680ULL);           //     27,648
  int*            rowptr = (int*)(ws + 100067328ULL);             //     27,648
  int*            colx   = (int*)(ws + 100094976ULL);             //    196,608
  __hip_bfloat16* xw2 = Wcatb;   // alias: Wcatb dead after k_wagg
  __hip_bfloat16* h2  = h1;      // alias: h1 dead after k_gemm2
  float*          xw3 = P;       // alias: P dead after k_transp

  k_prep<<<1, 1024, 0, stream>>>(ei, E, Wg1, S, rowptr, dinv, colx);
  k_wcat<<<(MPAD * (K2 / 8) + 255) / 256, 256, 0, stream>>>(Wx, Wy, Wz2, bx, by, bz2, Wcatb);
  k_img_reduce<<<BATCH * C720 / 4, 256, 0, stream>>>(img, Wg1, P, gT);
  k_head1<<<dim3(12544 / 8, 2), 256, 0, stream>>>(Wz1, bz1, Ww1, bw1, gT, Z1T, W1T);
  k_w1m<<<(224 * 32 + 255) / 256, 256, 0, stream>>>(W1T, w1m);
  k_coordw<<<(NV + 7) / 8, 256, 0, stream>>>(Ww2, bw2, w1m, out);
  k_passem_z<<<224, 256, 0, stream>>>(Z1T, Wg1, P);
  k_transp<<<dim3(K2 / 64, NBIG / 64), 256, 0, stream>>>(P, S, PT);
  k_wagg<<<MPAD / 4, 256, 0, stream>>>(Wcatb, rowptr, colx, dinv, Waggb);
  k_mfma_gemm<<<dim3(MPAD / 128, NBIG / 128), 256, 0, stream>>>(Waggb, PT, bg1, h1);
  k_gemm2<<<BATCH * NV / 8, 256, 0, stream>>>(h1, Wg2, xw2);
  k_agg2<<<BATCH * (NV / 2) / 4, 256, 0, stream>>>(xw2, rowptr, colx, dinv, bg2, h2);
  k_gemm3<<<(BATCH * NV + 255) / 256, 256, 0, stream>>>(h2, Wg3, xw3);
  k_agg3<<<(BATCH * NV + 255) / 256, 256, 0, stream>>>(xw3, rowptr, colx, dinv, bg3, out);
}